// Round 5
// baseline (174.645 us; speedup 1.0000x reference)
//
#include <hip/hip_runtime.h>

#define VOCAB 4096
#define SLICES 8
#define SLICE 512            // codes per slice (8-way split per point)
#define HALF 256             // pair (j, j+HALF) within a slice -> packed lanes

typedef float v2f __attribute__((ext_vector_type(2)));

// 32-byte pair record: component k of codes (gA, gB) packed as float2.
struct __align__(32) PkRec {
  v2f c0, c1, c2, cc;
};

// Empty-asm register barrier: forces the value into a VGPR, preventing
// fma-contraction / reassociation across it. Emits no instruction.
__device__ __forceinline__ float opaque(float x) {
  asm volatile("" : "+v"(x));
  return x;
}

// Prep: one thread per pair record r in [0, 2048).
// Slice s = r>>8, j = r&255; codes gA = s*512 + j, gB = gA + 256.
// cc = ((e0*e0 + e1*e1) + e2*e2) rounded exactly like numpy (each product
// and sum individually rounded f32). Also zero the loss slot.
__global__ __launch_bounds__(256) void vq_prep_kernel(
    const float* __restrict__ cb, PkRec* __restrict__ cw,
    float* __restrict__ loss_slot) {
  int r = blockIdx.x * 256 + threadIdx.x;
  if (r == 0) *loss_slot = 0.0f;
  if (r >= (VOCAB / 2)) return;
  int s = r >> 8;
  int j = r & (HALF - 1);
  int gA = s * SLICE + j;
  int gB = gA + HALF;

  float a0 = cb[3 * gA + 0], a1 = cb[3 * gA + 1], a2 = cb[3 * gA + 2];
  float b0 = cb[3 * gB + 0], b1 = cb[3 * gB + 1], b2 = cb[3 * gB + 2];

  float pa0 = opaque(a0 * a0), pa1 = opaque(a1 * a1), pa2 = opaque(a2 * a2);
  float ccA = opaque(opaque(pa0 + pa1) + pa2);
  float pb0 = opaque(b0 * b0), pb1 = opaque(b1 * b1), pb2 = opaque(b2 * b2);
  float ccB = opaque(opaque(pb0 + pb1) + pb2);

  PkRec rec;
  rec.c0 = (v2f){a0, b0};
  rec.c1 = (v2f){a1, b1};
  rec.c2 = (v2f){a2, b2};
  rec.cc = (v2f){ccA, ccB};
  cw[r] = rec;
}

// Main: block = 512 threads = 64 points x 8 codebook slices.
// 1024 blocks x 8 waves -> up to 32 waves/CU.
__global__ __launch_bounds__(512) void vq_kernel(
    const float* __restrict__ feats, const PkRec* __restrict__ cw,
    const float* __restrict__ cb, float* __restrict__ out_quant,
    float* __restrict__ out_idx, float* __restrict__ out_loss, int npts) {
  __shared__ float sB[512];
  __shared__ int sI[512];
  __shared__ double sL[64];

  const int tid = threadIdx.x;
  const int lane = tid & 63;
  const int s = tid >> 6;
  const int p = blockIdx.x * 64 + lane;

  const float x0 = feats[3 * p + 0];
  const float x1 = feats[3 * p + 1];
  const float x2 = feats[3 * p + 2];

  // ||x||^2 exactly as numpy: products rounded, then ((p0+p1)+p2)
  float xp0 = opaque(x0 * x0);
  float xp1 = opaque(x1 * x1);
  float xp2 = opaque(x2 * x2);
  const float a = opaque(opaque(xp0 + xp1) + xp2);

  v2f xx0 = (v2f){x0, x0};
  v2f xx1 = (v2f){x1, x1};
  v2f xx2 = (v2f){x2, x2};
  v2f aa = (v2f){a, a};
  v2f n2 = (v2f){-2.0f, -2.0f};

  // Force the record stream through VGPR addressing -> global_load_dwordx4
  // (per-lane uniform address = L1 broadcast), so pk operands live in VGPRs.
  const float4* recs = (const float4*)(cw + s * HALF);
  asm("" : "+v"(recs));

  // Two argmin chains (codes j and j+256 of this slice) ride the packed lanes.
  float bestA = 3.4e38f, bestB = 3.4e38f;
  int jA = 0, jB = 0;
#pragma unroll 4
  for (int j = 0; j < HALF; ++j) {
    float4 f0 = recs[2 * j];       // {c0A,c0B,c1A,c1B}
    float4 f1 = recs[2 * j + 1];   // {c2A,c2B,ccA,ccB}
    v2f c0 = (v2f){f0.x, f0.y};
    v2f c1 = (v2f){f0.z, f0.w};
    v2f c2 = (v2f){f1.x, f1.y};
    v2f cc = (v2f){f1.z, f1.w};
    // packed dot, fma ascending k: per-half rounding == scalar fmaf chain
    v2f m, t, d;
    asm("v_pk_mul_f32 %0, %1, %2" : "=v"(m) : "v"(c0), "v"(xx0));
    asm("v_pk_fma_f32 %0, %1, %2, %0" : "+v"(m) : "v"(c1), "v"(xx1));
    asm("v_pk_fma_f32 %0, %1, %2, %0" : "+v"(m) : "v"(c2), "v"(xx2));
    // t = a - 2*m  (2*m exact, so fma(-2,m,a) is value-identical)
    asm("v_pk_fma_f32 %0, %1, %2, %3" : "=v"(t) : "v"(m), "v"(n2), "v"(aa));
    asm("v_pk_add_f32 %0, %1, %2" : "=v"(d) : "v"(t), "v"(cc));
    float dA = d.x, dB = d.y;
    if (dA < bestA) jA = j;          // strict <: first-occurrence min
    bestA = fminf(dA, bestA);        // v_min_f32; equal keeps same value
    if (dB < bestB) jB = j;
    bestB = fminf(dB, bestB);
  }
  // combine halves: A spans lower indices; strict < keeps earliest on ties
  float best = bestA;
  int bi = s * SLICE + jA;
  if (bestB < best) { best = bestB; bi = s * SLICE + HALF + jB; }

  sB[tid] = best;
  sI[tid] = bi;
  __syncthreads();

  if (tid < 64) {
    // combine slices in ascending-index order; strict < keeps earliest
#pragma unroll
    for (int k = 1; k < SLICES; ++k) {
      float v = sB[tid + 64 * k];
      if (v < best) { best = v; bi = sI[tid + 64 * k]; }
    }
    float q0 = cb[3 * bi + 0];
    float q1 = cb[3 * bi + 1];
    float q2 = cb[3 * bi + 2];
    // straight-through: t = q - x (f32), out = x + t (f32), like reference
    float t0 = q0 - x0, t1 = q1 - x1, t2 = q2 - x2;
    out_quant[3 * p + 0] = x0 + t0;
    out_quant[3 * p + 1] = x1 + t1;
    out_quant[3 * p + 2] = x2 + t2;
    out_idx[p] = (float)bi;
    sL[tid] = (double)t0 * t0 + (double)t1 * t1 + (double)t2 * t2;
  }
  __syncthreads();

  if (tid == 0) {
    double acc = 0.0;
#pragma unroll 8
    for (int k = 0; k < 64; ++k) acc += sL[k];
    // loss = mean((q-x)^2) + 0.25*mean((x-q)^2) = 1.25 * sum / (npts*3)
    atomicAdd(out_loss, (float)(acc * (1.25 / ((double)npts * 3.0))));
  }
}

extern "C" void kernel_launch(void* const* d_in, const int* in_sizes, int n_in,
                              void* d_out, int out_size, void* d_ws,
                              size_t ws_size, hipStream_t stream) {
  const float* feats = (const float*)d_in[0];      // (B*L, 3) f32
  const float* cb = (const float*)d_in[1];         // (4096, 3) f32
  const int npts = in_sizes[0] / 3;                // 65536

  float* out = (float*)d_out;
  float* out_quant = out;                          // npts*3 elems
  float* out_idx = out + in_sizes[0];              // npts elems
  float* out_loss = out + in_sizes[0] + npts;      // 1 elem

  PkRec* cw = (PkRec*)d_ws;                        // 2048 * 32 B = 64 KB

  vq_prep_kernel<<<(VOCAB / 2) / 256, 256, 0, stream>>>(cb, cw, out_loss);
  vq_kernel<<<npts / 64, 512, 0, stream>>>(feats, cw, cb, out_quant, out_idx,
                                           out_loss, npts);
}

// Round 6
// 107.568 us; speedup vs baseline: 1.6236x; 1.6236x over previous
//
#include <hip/hip_runtime.h>

#define VOCAB 4096
#define SLICES 8
#define SLICE 512            // codes per slice (8-way split per point)
#define GRP 8                // codes per min-tree group
#define NGRP (SLICE / GRP)   // 64 groups per slice

// Empty-asm register barrier: forces the value into a VGPR, preventing
// fma-contraction / reassociation across it. Emits no instruction.
__device__ __forceinline__ float opaque(float x) {
  asm volatile("" : "+v"(x));
  return x;
}

// Prep: pack per-code {e0, e1, e2, ||e||^2_f32} into ws as float4, where
// ||e||^2 is rounded exactly like numpy: ((e0*e0 + e1*e1) + e2*e2), each
// product and sum individually rounded in f32. Also zero the loss slot.
__global__ __launch_bounds__(256) void vq_prep_kernel(
    const float* __restrict__ cb, float4* __restrict__ cw,
    float* __restrict__ loss_slot) {
  int j = blockIdx.x * 256 + threadIdx.x;
  if (j == 0) *loss_slot = 0.0f;
  if (j < VOCAB) {
    float e0 = cb[3 * j + 0];
    float e1 = cb[3 * j + 1];
    float e2 = cb[3 * j + 2];
    float p0 = opaque(e0 * e0);
    float p1 = opaque(e1 * e1);
    float p2 = opaque(e2 * e2);
    float c = opaque(opaque(p0 + p1) + p2);
    cw[j] = make_float4(e0, e1, e2, c);
  }
}

// Distance with numpy's exact f32 rounding:
//   m = x.e (fma ascending k, first term single-rounded mul)
//   d = (a - 2m) + c   [a-2m via fma(-2,m,a): 2m is exact, value-identical]
__device__ __forceinline__ float dist_f32(float x0, float x1, float x2,
                                          float a, float4 cd) {
  float m = fmaf(x2, cd.z, fmaf(x1, cd.y, x0 * cd.x));
  return fmaf(-2.0f, m, a) + cd.w;
}

// Main: block = 512 threads = 64 points x 8 codebook slices.
// 1024 blocks x 8 waves -> up to 32 waves/CU.
__global__ __launch_bounds__(512) void vq_kernel(
    const float* __restrict__ feats, const float4* __restrict__ cw,
    float* __restrict__ out_quant, float* __restrict__ out_idx,
    float* __restrict__ out_loss, int npts) {
  __shared__ float sB[512];
  __shared__ int sI[512];
  __shared__ double sL[64];

  const int tid = threadIdx.x;
  const int lane = tid & 63;
  // slice id is wave-uniform; force SGPR so code records stream via s_load
  const int s = __builtin_amdgcn_readfirstlane(tid >> 6);
  const int p = blockIdx.x * 64 + lane;

  const float x0 = feats[3 * p + 0];
  const float x1 = feats[3 * p + 1];
  const float x2 = feats[3 * p + 2];

  // ||x||^2 exactly as numpy: products rounded, then ((p0+p1)+p2)
  float xp0 = opaque(x0 * x0);
  float xp1 = opaque(x1 * x1);
  float xp2 = opaque(x2 * x2);
  const float a = opaque(opaque(xp0 + xp1) + xp2);

  const float4* cs = cw + s * SLICE;

  // Group-min scan: track only (best value, winning group base).
  // All distances are >= (|x|-|e|)^2 >> 0: positive, no NaN -> fminf exact.
  float best = 3.4e38f;
  int gbase = 0;
#pragma unroll 2
  for (int g = 0; g < NGRP; ++g) {
    const float4* gp = cs + g * GRP;  // wave-uniform -> s_load_dwordx16 x2
    float d0 = dist_f32(x0, x1, x2, a, gp[0]);
    float d1 = dist_f32(x0, x1, x2, a, gp[1]);
    float d2 = dist_f32(x0, x1, x2, a, gp[2]);
    float d3 = dist_f32(x0, x1, x2, a, gp[3]);
    float d4 = dist_f32(x0, x1, x2, a, gp[4]);
    float d5 = dist_f32(x0, x1, x2, a, gp[5]);
    float d6 = dist_f32(x0, x1, x2, a, gp[6]);
    float d7 = dist_f32(x0, x1, x2, a, gp[7]);
    float gm = fminf(fminf(fminf(d0, d1), fminf(d2, d3)),
                     fminf(fminf(d4, d5), fminf(d6, d7)));
    // strict <: keeps the EARLIEST group attaining the running min
    if (gm < best) { best = gm; gbase = g; }
  }
  gbase = s * SLICE + gbase * GRP;

  sB[tid] = best;
  sI[tid] = gbase;
  __syncthreads();

  if (tid < 64) {
    // combine slices in ascending-index order; strict < keeps earliest group
#pragma unroll
    for (int k = 1; k < SLICES; ++k) {
      float v = sB[tid + 64 * k];
      if (v < best) { best = v; gbase = sI[tid + 64 * k]; }
    }
    // Index recovery: rescan the winning 8-code group with identical
    // rounding; first d == best is np.argmin's first-occurrence winner.
    int bi = gbase;
    float q0 = 0.0f, q1 = 0.0f, q2 = 0.0f;
    bool found = false;
#pragma unroll
    for (int k = 0; k < GRP; ++k) {
      float4 cd = cw[gbase + k];
      float d = dist_f32(x0, x1, x2, a, cd);
      if (!found && d == best) {
        found = true;
        bi = gbase + k;
        q0 = cd.x; q1 = cd.y; q2 = cd.z;
      }
    }
    // straight-through: t = q - x (f32), out = x + t (f32), like reference
    float t0 = q0 - x0, t1 = q1 - x1, t2 = q2 - x2;
    out_quant[3 * p + 0] = x0 + t0;
    out_quant[3 * p + 1] = x1 + t1;
    out_quant[3 * p + 2] = x2 + t2;
    out_idx[p] = (float)bi;
    sL[tid] = (double)t0 * t0 + (double)t1 * t1 + (double)t2 * t2;
  }
  __syncthreads();

  if (tid == 0) {
    double acc = 0.0;
#pragma unroll 8
    for (int k = 0; k < 64; ++k) acc += sL[k];
    // loss = mean((q-x)^2) + 0.25*mean((x-q)^2) = 1.25 * sum / (npts*3)
    atomicAdd(out_loss, (float)(acc * (1.25 / ((double)npts * 3.0))));
  }
}

extern "C" void kernel_launch(void* const* d_in, const int* in_sizes, int n_in,
                              void* d_out, int out_size, void* d_ws,
                              size_t ws_size, hipStream_t stream) {
  const float* feats = (const float*)d_in[0];      // (B*L, 3) f32
  const float* cb = (const float*)d_in[1];         // (4096, 3) f32
  const int npts = in_sizes[0] / 3;                // 65536

  float* out = (float*)d_out;
  float* out_quant = out;                          // npts*3 elems
  float* out_idx = out + in_sizes[0];              // npts elems
  float* out_loss = out + in_sizes[0] + npts;      // 1 elem

  float4* cw = (float4*)d_ws;                      // 4096 * 16 B = 64 KB

  vq_prep_kernel<<<VOCAB / 256, 256, 0, stream>>>(cb, cw, out_loss);
  vq_kernel<<<npts / 64, 512, 0, stream>>>(feats, cw, out_quant, out_idx,
                                           out_loss, npts);
}